// Round 11
// baseline (4575.874 us; speedup 1.0000x reference)
//
#include <hip/hip_runtime.h>
#include <hip/hip_bf16.h>

typedef short bf16x8 __attribute__((ext_vector_type(8)));
typedef float f32x4  __attribute__((ext_vector_type(4)));

#define DIN  4096
#define DOUT 4096
#define MTOT 8192
#define RNK  32
#define NT   128  // K-tiles of BK=32

union Pk8 { __hip_bfloat16 h[8]; uint4 u; bf16x8 v; };

__device__ __forceinline__ uint4 pack8(float a0,float a1,float a2,float a3,
                                       float b0,float b1,float b2,float b3){
  Pk8 p;
  p.h[0]=__float2bfloat16(a0); p.h[1]=__float2bfloat16(a1);
  p.h[2]=__float2bfloat16(a2); p.h[3]=__float2bfloat16(a3);
  p.h[4]=__float2bfloat16(b0); p.h[5]=__float2bfloat16(b1);
  p.h[6]=__float2bfloat16(b2); p.h[7]=__float2bfloat16(b3);
  return p.u;
}
__device__ __forceinline__ bf16x8 pack8v(float a0,float a1,float a2,float a3,
                                         float b0,float b1,float b2,float b3){
  Pk8 p;
  p.h[0]=__float2bfloat16(a0); p.h[1]=__float2bfloat16(a1);
  p.h[2]=__float2bfloat16(a2); p.h[3]=__float2bfloat16(a3);
  p.h[4]=__float2bfloat16(b0); p.h[5]=__float2bfloat16(b1);
  p.h[6]=__float2bfloat16(b2); p.h[7]=__float2bfloat16(b3);
  return p.v;
}

__device__ __forceinline__ void gload_lds16(const void* g, void* l){
  __builtin_amdgcn_global_load_lds(
      (const __attribute__((address_space(1))) unsigned int*)g,
      (__attribute__((address_space(3))) unsigned int*)l, 16, 0, 0);
}

#define MFMA(A,B,C) __builtin_amdgcn_mfma_f32_16x16x32_bf16(A,B,C,0,0,0)
#define BAR   asm volatile("s_barrier" ::: "memory")
#define SB0   __builtin_amdgcn_sched_barrier(0)
#define PRIO1 __builtin_amdgcn_s_setprio(1)
#define PRIO0 __builtin_amdgcn_s_setprio(0)

// ---------------- prep: W fp32 -> bf16 ----------------
__global__ __launch_bounds__(256) void k_conv_w(const float* __restrict__ W,
                                                __hip_bfloat16* __restrict__ Wb){
  size_t i = ((size_t)blockIdx.x*256 + threadIdx.x) * 8;
  float4 a = *(const float4*)(W + i);
  float4 b = *(const float4*)(W + i + 4);
  *(uint4*)(Wb + i) = pack8(a.x,a.y,a.z,a.w,b.x,b.y,b.z,b.w);
}

// ---------------- prep: A -> At[32][4096] bf16 ; B -> Bt[4096][32] bf16 ----
__global__ __launch_bounds__(256) void k_conv_ab(const float* __restrict__ A,
                                                 const float* __restrict__ B,
                                                 __hip_bfloat16* __restrict__ At,
                                                 __hip_bfloat16* __restrict__ Bt){
  int idx = blockIdx.x*256 + threadIdx.x;
  if (idx < DIN*RNK){
    int k = idx >> 5, r = idx & 31;
    At[(size_t)r*DIN + k] = __float2bfloat16(A[(size_t)k*RNK + r]);
  } else {
    int j = idx - DIN*RNK;
    int n = j >> 5, k = j & 31;
    Bt[(size_t)n*RNK + k] = __float2bfloat16(B[(size_t)k*DOUT + n]);
  }
}

// ---------------- fused: x -> x_bf16 ; t = (x*mask) @ A  ------------------
__global__ __launch_bounds__(256) void k_xt(const float* __restrict__ x,
                                            const float* __restrict__ mk,
                                            const __hip_bfloat16* __restrict__ At,
                                            __hip_bfloat16* __restrict__ xb,
                                            __hip_bfloat16* __restrict__ tb){
  __shared__ float sred[4*512];   // 8 KB
  const int t = threadIdx.x, w = t >> 6, l = t & 63;
  const int r0 = blockIdx.x * 16;
  const int lane15 = l & 15, kb = l >> 4;
  const size_t rowbase = (size_t)(r0 + lane15) * DIN;
  const int kbase = w * 1024;

  f32x4 acc0 = {0.f,0.f,0.f,0.f}, acc1 = {0.f,0.f,0.f,0.f};
  const __hip_bfloat16* at0 = At + (size_t)lane15*DIN;
  const __hip_bfloat16* at1 = At + (size_t)(16+lane15)*DIN;

  #pragma unroll 2
  for (int kt = 0; kt < 32; ++kt){
    const int k0 = kbase + kt*32 + kb*8;
    float4 xa = *(const float4*)(x  + rowbase + k0);
    float4 xc = *(const float4*)(x  + rowbase + k0 + 4);
    float4 ma = *(const float4*)(mk + rowbase + k0);
    float4 mc = *(const float4*)(mk + rowbase + k0 + 4);
    *(uint4*)(xb + rowbase + k0) = pack8(xa.x,xa.y,xa.z,xa.w,xc.x,xc.y,xc.z,xc.w);
    bf16x8 af = pack8v(xa.x*ma.x,xa.y*ma.y,xa.z*ma.z,xa.w*ma.w,
                       xc.x*mc.x,xc.y*mc.y,xc.z*mc.z,xc.w*mc.w);
    bf16x8 b0 = *(const bf16x8*)(at0 + k0);
    bf16x8 b1 = *(const bf16x8*)(at1 + k0);
    acc0 = MFMA(af, b0, acc0);
    acc1 = MFMA(af, b1, acc1);
  }

  #pragma unroll
  for (int r = 0; r < 4; ++r){
    sred[(w*64+l)*8 + r]     = acc0[r];
    sred[(w*64+l)*8 + 4 + r] = acc1[r];
  }
  __syncthreads();
  #pragma unroll
  for (int e2 = 0; e2 < 2; ++e2){
    int e  = t*2 + e2;
    int el = e >> 3, er = e & 7;
    float s = sred[el*8+er] + sred[512+el*8+er] + sred[1024+el*8+er] + sred[1536+el*8+er];
    int col  = (er>>2)*16 + (el & 15);
    int orow = (el>>4)*4 + (er & 3);
    tb[(size_t)(r0 + orow)*RNK + col] = __float2bfloat16(s);
  }
}

// ---------------- main GEMM: 256x256, BK=32, 8 waves, 64KB LDS -> 2 blocks/CU.
// r5's proven 16x16 frag layout + swizzle (0 conflicts). 2 regions per K-tile:
//  rA(t): read A(t) m4-7 [ASEG(b)] ; stage B(t+2)->BSEG(b) [disjoint segs];
//         MFMA m0-3 (aE x bCur)
//  rB(t): vmcnt(2) [forces S(t+1); issue->force gap 2-3 regions];
//         read A(t+1) m0-3 + B(t+1) [buf b^1]; stage A(t+2)->ASEG(b);
//         MFMA m4-7 (aO x bCur)
// Every overwritten seg had its last read >= 1 barrier earlier (ledger sim'd).
__global__ __launch_bounds__(512, 4) void k_main6(const __hip_bfloat16* __restrict__ xb,
                                                  const __hip_bfloat16* __restrict__ Wb,
                                                  const __hip_bfloat16* __restrict__ tb,
                                                  const __hip_bfloat16* __restrict__ Bt,
                                                  float* __restrict__ out){
  __shared__ __align__(16) __hip_bfloat16 lds[32768];   // 64 KiB
  const int tid = threadIdx.x;
  const int l  = tid & 63, w = tid >> 6;
  const int wm = w >> 2,  wn = w & 3;       // 2x4 wave grid; wave tile 128x64
  const int lr = l & 15,  kb = l >> 4;
  const int ch = (kb ^ ((l >> 1) & 3)) & 3;             // r5 swizzled chunk
  const int lpos = lr*32 + ch*8;
  const int aoff = wm*4096 + lpos;                      // + m*512 in ASEG
  const int boff = wn*2048 + lpos;                      // + n*512 in BSEG
  const int g_row = tid >> 2;
  const int g_ch  = (((tid & 3) ^ ((tid >> 3) & 3))) * 8;

  // 8 XCD regions of 8m x 8n (tile grid 32m x 16n); bijective; co-resident
  // blocks (bid, bid+256) share the same XCD region.
  const int bid  = blockIdx.x;
  const int xcd  = bid & 7;
  const int idx  = bid >> 3;
  const int bm0  = (((xcd >> 1) << 3) + (idx & 7)) * 256;
  const int bn0  = (((xcd & 1) << 3) + (idx >> 3)) * 256;

  f32x4 acc[8][4];

  // ---- LoRA prologue: acc = t_frag @ Bt_frag (K=32), initializes acc ----
  {
    const __hip_bfloat16* tp = tb + (size_t)(bm0 + wm*128 + lr)*RNK + kb*8;
    const __hip_bfloat16* bp = Bt + (size_t)(bn0 + wn*64  + lr)*RNK + kb*8;
    bf16x8 tf[8], bf[4];
    #pragma unroll
    for (int m = 0; m < 8; ++m) tf[m] = *(const bf16x8*)(tp + m*16*RNK);
    #pragma unroll
    for (int n = 0; n < 4; ++n) bf[n] = *(const bf16x8*)(bp + n*16*RNK);
    const f32x4 z = {0.f,0.f,0.f,0.f};
    #pragma unroll
    for (int m = 0; m < 8; ++m)
      #pragma unroll
      for (int n = 0; n < 4; ++n)
        acc[m][n] = MFMA(tf[m], bf[n], z);
  }
  asm volatile("" ::: "memory");

  // stage one 16KB seg (buf bb, ab: 0=A(xb) 1=B(Wb), tile kt); 2 loads/thread
  auto STAGE = [&](int bb, int ab, int kt){
    const __hip_bfloat16* g = ab ? Wb : xb;
    const int base0 = ab ? bn0 : bm0;
    const int segb  = bb*16384 + ab*8192;
    #pragma unroll
    for (int i = 0; i < 2; ++i){
      const __hip_bfloat16* src = g + (size_t)(base0 + i*128 + g_row)*DIN
                                    + kt*32 + g_ch;
      gload_lds16(src, (void*)&lds[segb + i*4096 + w*512]);
    }
  };

  #define ABASE(b) ((b)*16384)
  #define BBASE(b) ((b)*16384 + 8192)
  #define LDV(off) (*(const bf16x8*)&lds[(off)])

  // prologue: A0,B0 then B1,A1 ; vmcnt(4) leaves S(1) in flight, forces tile0
  STAGE(0,0,0); STAGE(0,1,0); STAGE(1,1,1); STAGE(1,0,1);
  asm volatile("s_waitcnt vmcnt(4)" ::: "memory");
  BAR; SB0;

  bf16x8 aE[4], aO[4], bX[4], bY[4];
  #pragma unroll
  for (int m = 0; m < 4; ++m) aE[m] = LDV(ABASE(0) + aoff + m*512);
  #pragma unroll
  for (int n = 0; n < 4; ++n) bX[n] = LDV(BBASE(0) + boff + n*512);

  #define ONE_TILE(T, BC, BN_)                                                 \
  {                                                                            \
    const int b = (T)&1, bo = b^1;                                             \
    /* rA */                                                                   \
    BAR; SB0;                                                                  \
    _Pragma("unroll") for (int m = 0; m < 4; ++m)                              \
      aO[m] = LDV(ABASE(b) + aoff + (4+m)*512);                                \
    if ((T)+2 < NT) STAGE(b, 1, (T)+2);                                        \
    PRIO1;                                                                     \
    _Pragma("unroll") for (int m = 0; m < 4; ++m)                              \
      _Pragma("unroll") for (int n = 0; n < 4; ++n)                            \
        acc[m][n] = MFMA(aE[m], BC[n], acc[m][n]);                             \
    PRIO0;                                                                     \
    /* rB */                                                                   \
    BAR; SB0;                                                                  \
    if ((T)+2 < NT)      asm volatile("s_waitcnt vmcnt(2)" ::: "memory");      \
    else if ((T)+1 < NT) asm volatile("s_waitcnt vmcnt(0)" ::: "memory");      \
    if ((T)+1 < NT){                                                           \
      _Pragma("unroll") for (int m = 0; m < 4; ++m)                            \
        aE[m] = LDV(ABASE(bo) + aoff + m*512);                                 \
      _Pragma("unroll") for (int n = 0; n < 4; ++n)                            \
        BN_[n] = LDV(BBASE(bo) + boff + n*512);                                \
    }                                                                          \
    if ((T)+2 < NT) STAGE(b, 0, (T)+2);                                        \
    PRIO1;                                                                     \
    _Pragma("unroll") for (int m = 0; m < 4; ++m)                              \
      _Pragma("unroll") for (int n = 0; n < 4; ++n)                            \
        acc[4+m][n] = MFMA(aO[m], BC[n], acc[4+m][n]);                         \
    PRIO0;                                                                     \
  }

  for (int tt = 0; tt < NT; tt += 2){
    ONE_TILE(tt,   bX, bY);
    ONE_TILE(tt+1, bY, bX);
  }

  // ---- epilogue: C write (f32) ----
  const int orow = bm0 + wm*128 + (l>>4)*4;
  const int ocol = bn0 + wn*64  + (l&15);
  #pragma unroll
  for (int m = 0; m < 8; ++m)
    #pragma unroll
    for (int n = 0; n < 4; ++n)
      #pragma unroll
      for (int r = 0; r < 4; ++r)
        out[(size_t)(orow + m*16 + r)*DOUT + ocol + n*16] = acc[m][n][r];
  #undef LDV
  #undef ABASE
  #undef BBASE
  #undef ONE_TILE
}

// ---------------- fallback (ws too small): slow but correct fp32 ----------
__global__ void fb_t(const float* __restrict__ x, const float* __restrict__ mk,
                     const float* __restrict__ A, float* __restrict__ tf){
  const int m = blockIdx.x, t = threadIdx.x;
  float acc[RNK];
  #pragma unroll
  for (int r = 0; r < RNK; ++r) acc[r] = 0.f;
  for (int k = t; k < DIN; k += 256){
    float xm = x[(size_t)m*DIN + k] * mk[(size_t)m*DIN + k];
    #pragma unroll
    for (int r = 0; r < RNK; ++r) acc[r] += xm * A[(size_t)k*RNK + r];
  }
  #pragma unroll
  for (int r = 0; r < RNK; ++r){
    float v = acc[r];
    for (int o = 32; o; o >>= 1) v += __shfl_down(v, o);
    if ((t & 63) == 0) atomicAdd(&tf[(size_t)m*RNK + r], v);
  }
}

__global__ void fb_out(const float* __restrict__ x, const float* __restrict__ W,
                       const float* __restrict__ B, const float* __restrict__ tf,
                       float* __restrict__ out){
  size_t idx = (size_t)blockIdx.x*256 + threadIdx.x;
  int m = (int)(idx >> 12), n = (int)(idx & 4095);
  float acc = 0.f;
  for (int k = 0; k < DIN; ++k)
    acc += x[(size_t)m*DIN + k] * W[(size_t)n*DIN + k];
  #pragma unroll
  for (int r = 0; r < RNK; ++r)
    acc += tf[(size_t)m*RNK + r] * B[(size_t)r*DOUT + n];
  out[idx] = acc;
}

extern "C" void kernel_launch(void* const* d_in, const int* in_sizes, int n_in,
                              void* d_out, int out_size, void* d_ws, size_t ws_size,
                              hipStream_t stream) {
  const float* x  = (const float*)d_in[0];
  const float* W  = (const float*)d_in[1];
  const float* A  = (const float*)d_in[2];
  const float* B  = (const float*)d_in[3];
  const float* mk = (const float*)d_in[4];
  float* out = (float*)d_out;

  const size_t OFF_XB = 0;
  const size_t OFF_WB = OFF_XB + (size_t)MTOT*DIN*2;
  const size_t OFF_TB = OFF_WB + (size_t)DOUT*DIN*2;
  const size_t OFF_AT = OFF_TB + (size_t)MTOT*RNK*2;
  const size_t OFF_BT = OFF_AT + (size_t)RNK*DIN*2;
  const size_t NEED   = OFF_BT + (size_t)DIN*RNK*2;

  if (ws_size >= NEED){
    char* ws = (char*)d_ws;
    __hip_bfloat16* xb = (__hip_bfloat16*)(ws + OFF_XB);
    __hip_bfloat16* Wb = (__hip_bfloat16*)(ws + OFF_WB);
    __hip_bfloat16* tb = (__hip_bfloat16*)(ws + OFF_TB);
    __hip_bfloat16* At = (__hip_bfloat16*)(ws + OFF_AT);
    __hip_bfloat16* Bt = (__hip_bfloat16*)(ws + OFF_BT);

    k_conv_w <<<(DOUT*(size_t)DIN)/(256*8), 256, 0, stream>>>(W, Wb);
    k_conv_ab<<<(2*DIN*RNK)/256,            256, 0, stream>>>(A, B, At, Bt);
    k_xt     <<<MTOT/16,                    256, 0, stream>>>(x, mk, At, xb, tb);
    k_main6  <<<(MTOT/256)*(DOUT/256),      512, 0, stream>>>(xb, Wb, tb, Bt, out);
  } else {
    float* tf = (float*)d_ws;
    hipMemsetAsync(tf, 0, (size_t)MTOT*RNK*4, stream);
    fb_t  <<<MTOT, 256, 0, stream>>>(x, mk, A, tf);
    fb_out<<<((size_t)MTOT*DOUT)/256, 256, 0, stream>>>(x, W, B, tf, out);
  }
}

// Round 12
// 358.708 us; speedup vs baseline: 12.7565x; 12.7565x over previous
//
#include <hip/hip_runtime.h>
#include <hip/hip_bf16.h>

typedef short bf16x8 __attribute__((ext_vector_type(8)));
typedef float f32x4  __attribute__((ext_vector_type(4)));

#define DIN  4096
#define DOUT 4096
#define MTOT 8192
#define RNK  32
#define NT   64   // K-tiles of BK=64

union Pk8 { __hip_bfloat16 h[8]; uint4 u; bf16x8 v; };

__device__ __forceinline__ uint4 pack8(float a0,float a1,float a2,float a3,
                                       float b0,float b1,float b2,float b3){
  Pk8 p;
  p.h[0]=__float2bfloat16(a0); p.h[1]=__float2bfloat16(a1);
  p.h[2]=__float2bfloat16(a2); p.h[3]=__float2bfloat16(a3);
  p.h[4]=__float2bfloat16(b0); p.h[5]=__float2bfloat16(b1);
  p.h[6]=__float2bfloat16(b2); p.h[7]=__float2bfloat16(b3);
  return p.u;
}
__device__ __forceinline__ bf16x8 pack8v(float a0,float a1,float a2,float a3,
                                         float b0,float b1,float b2,float b3){
  Pk8 p;
  p.h[0]=__float2bfloat16(a0); p.h[1]=__float2bfloat16(a1);
  p.h[2]=__float2bfloat16(a2); p.h[3]=__float2bfloat16(a3);
  p.h[4]=__float2bfloat16(b0); p.h[5]=__float2bfloat16(b1);
  p.h[6]=__float2bfloat16(b2); p.h[7]=__float2bfloat16(b3);
  return p.v;
}

__device__ __forceinline__ void gload_lds16(const void* g, void* l){
  __builtin_amdgcn_global_load_lds(
      (const __attribute__((address_space(1))) unsigned int*)g,
      (__attribute__((address_space(3))) unsigned int*)l, 16, 0, 0);
}

#define MFMA(A,B,C) __builtin_amdgcn_mfma_f32_16x16x32_bf16(A,B,C,0,0,0)
#define BAR   asm volatile("s_barrier" ::: "memory")
#define SB0   __builtin_amdgcn_sched_barrier(0)
#define PRIO1 __builtin_amdgcn_s_setprio(1)
#define PRIO0 __builtin_amdgcn_s_setprio(0)

// ---------------- prep: W fp32 -> bf16 ----------------
__global__ __launch_bounds__(256) void k_conv_w(const float* __restrict__ W,
                                                __hip_bfloat16* __restrict__ Wb){
  size_t i = ((size_t)blockIdx.x*256 + threadIdx.x) * 8;
  float4 a = *(const float4*)(W + i);
  float4 b = *(const float4*)(W + i + 4);
  *(uint4*)(Wb + i) = pack8(a.x,a.y,a.z,a.w,b.x,b.y,b.z,b.w);
}

// ---------------- prep: A -> At[32][4096] bf16 ; B -> Bt[4096][32] bf16 ----
__global__ __launch_bounds__(256) void k_conv_ab(const float* __restrict__ A,
                                                 const float* __restrict__ B,
                                                 __hip_bfloat16* __restrict__ At,
                                                 __hip_bfloat16* __restrict__ Bt){
  int idx = blockIdx.x*256 + threadIdx.x;
  if (idx < DIN*RNK){
    int k = idx >> 5, r = idx & 31;
    At[(size_t)r*DIN + k] = __float2bfloat16(A[(size_t)k*RNK + r]);
  } else {
    int j = idx - DIN*RNK;
    int n = j >> 5, k = j & 31;
    Bt[(size_t)n*RNK + k] = __float2bfloat16(B[(size_t)k*DOUT + n]);
  }
}

// ---------------- fused: x -> x_bf16 ; t = (x*mask) @ A  ------------------
__global__ __launch_bounds__(256) void k_xt(const float* __restrict__ x,
                                            const float* __restrict__ mk,
                                            const __hip_bfloat16* __restrict__ At,
                                            __hip_bfloat16* __restrict__ xb,
                                            __hip_bfloat16* __restrict__ tb){
  __shared__ float sred[4*512];   // 8 KB
  const int t = threadIdx.x, w = t >> 6, l = t & 63;
  const int r0 = blockIdx.x * 16;
  const int lane15 = l & 15, kb = l >> 4;
  const size_t rowbase = (size_t)(r0 + lane15) * DIN;
  const int kbase = w * 1024;

  f32x4 acc0 = {0.f,0.f,0.f,0.f}, acc1 = {0.f,0.f,0.f,0.f};
  const __hip_bfloat16* at0 = At + (size_t)lane15*DIN;
  const __hip_bfloat16* at1 = At + (size_t)(16+lane15)*DIN;

  #pragma unroll 2
  for (int kt = 0; kt < 32; ++kt){
    const int k0 = kbase + kt*32 + kb*8;
    float4 xa = *(const float4*)(x  + rowbase + k0);
    float4 xc = *(const float4*)(x  + rowbase + k0 + 4);
    float4 ma = *(const float4*)(mk + rowbase + k0);
    float4 mc = *(const float4*)(mk + rowbase + k0 + 4);
    *(uint4*)(xb + rowbase + k0) = pack8(xa.x,xa.y,xa.z,xa.w,xc.x,xc.y,xc.z,xc.w);
    bf16x8 af = pack8v(xa.x*ma.x,xa.y*ma.y,xa.z*ma.z,xa.w*ma.w,
                       xc.x*mc.x,xc.y*mc.y,xc.z*mc.z,xc.w*mc.w);
    bf16x8 b0 = *(const bf16x8*)(at0 + k0);
    bf16x8 b1 = *(const bf16x8*)(at1 + k0);
    acc0 = MFMA(af, b0, acc0);
    acc1 = MFMA(af, b1, acc1);
  }

  #pragma unroll
  for (int r = 0; r < 4; ++r){
    sred[(w*64+l)*8 + r]     = acc0[r];
    sred[(w*64+l)*8 + 4 + r] = acc1[r];
  }
  __syncthreads();
  #pragma unroll
  for (int e2 = 0; e2 < 2; ++e2){
    int e  = t*2 + e2;
    int el = e >> 3, er = e & 7;
    float s = sred[el*8+er] + sred[512+el*8+er] + sred[1024+el*8+er] + sred[1536+el*8+er];
    int col  = (er>>2)*16 + (el & 15);
    int orow = (el>>4)*4 + (er & 3);
    tb[(size_t)(r0 + orow)*RNK + col] = __float2bfloat16(s);
  }
}

// ---------------- main GEMM: 256x256, BK=64, 8 waves, TWO regions per K-tile.
// r5's proven 16x16 frag layout + swizzle (0 conflicts) + XCD map (198 MB).
// Reads pipelined one region ahead; 32 MFMA + 12 ds_read + 2 STAGE + 1 barrier
// per region; vmcnt(8) at each region close (forces loads issued 2 regions
// earlier; tail vmcnt(4)/vmcnt(0) at t==NT-2).
// Stage ledger: R1(t) stages A0,B0(t+2)->buf b (segs last read in R2(t-1));
// R2(t) stages A1,B1(t+2)->buf b (segs last read in R1(t)). 1 barrier between
// every last-read and overwrite + full VMEM latency margin.
__global__ __launch_bounds__(512) void k_main7(const __hip_bfloat16* __restrict__ xb,
                                               const __hip_bfloat16* __restrict__ Wb,
                                               const __hip_bfloat16* __restrict__ tb,
                                               const __hip_bfloat16* __restrict__ Bt,
                                               float* __restrict__ out){
  __shared__ __align__(16) __hip_bfloat16 lds[65536];   // 128 KiB -> 1 block/CU
  const int tid = threadIdx.x;
  const int l  = tid & 63, w = tid >> 6;
  const int wm = w >> 2,  wn = w & 3;       // 2x4 wave grid; wave tile 128x64
  const int lr = l & 15,  kb = l >> 4;
  const int ch = (kb ^ ((l >> 1) & 3)) & 3;             // r5 swizzled chunk
  const int laneA = (wm*128 + lr)*32 + ch*8;            // + m*512 within seg
  const int laneB = (wn*64  + lr)*32 + ch*8;            // + n*512 within seg
  const int g_row = tid >> 2;
  const int g_ch  = (((tid & 3) ^ ((tid >> 3) & 3))) * 8;

  // 8 XCD regions of 8m x 8n (tile grid 32m x 16n); bijective
  const int bid  = blockIdx.x;
  const int xcd  = bid & 7;
  const int idx  = bid >> 3;
  const int bm0  = (((xcd >> 1) << 3) + (idx & 7)) * 256;
  const int bn0  = (((xcd & 1) << 3) + (idx >> 3)) * 256;

  f32x4 acc[8][4];

  // ---- LoRA prologue: acc = t_frag @ Bt_frag (K=32), initializes acc ----
  {
    const __hip_bfloat16* tp = tb + (size_t)(bm0 + wm*128 + lr)*RNK + kb*8;
    const __hip_bfloat16* bp = Bt + (size_t)(bn0 + wn*64  + lr)*RNK + kb*8;
    bf16x8 tf[8], bf[4];
    #pragma unroll
    for (int m = 0; m < 8; ++m) tf[m] = *(const bf16x8*)(tp + m*16*RNK);
    #pragma unroll
    for (int n = 0; n < 4; ++n) bf[n] = *(const bf16x8*)(bp + n*16*RNK);
    const f32x4 z = {0.f,0.f,0.f,0.f};
    #pragma unroll
    for (int m = 0; m < 8; ++m)
      #pragma unroll
      for (int n = 0; n < 4; ++n)
        acc[m][n] = MFMA(tf[m], bf[n], z);
  }
  asm volatile("" ::: "memory");

  // stage one 16KB seg (buf bb, ab: 0=A(xb) 1=B(Wb), khalf kh, tile kt)
  auto STAGE = [&](int bb, int ab, int kh, int kt){
    const __hip_bfloat16* g = ab ? Wb : xb;
    const int base0 = ab ? bn0 : bm0;
    const int segb  = bb*32768 + ab*16384 + kh*8192;
    #pragma unroll
    for (int i = 0; i < 2; ++i){
      const __hip_bfloat16* src = g + (size_t)(base0 + i*128 + g_row)*DIN
                                    + kt*64 + kh*32 + g_ch;
      gload_lds16(src, (void*)&lds[segb + i*4096 + w*512]);
    }
  };

  #define ASEG(bb,kh) ((bb)*32768 + (kh)*8192)
  #define BSEG(bb,kh) ((bb)*32768 + 16384 + (kh)*8192)
  #define LDV(off) (*(const bf16x8*)&lds[(off)])

  // prologue: t0 all 4 segs; t1 A0,B0 (virtual R1(-1)); t1 A1,B1 (virtual R2(-1))
  STAGE(0,0,0,0); STAGE(0,1,0,0); STAGE(0,0,1,0); STAGE(0,1,1,0);
  STAGE(1,0,0,1); STAGE(1,1,0,1);
  STAGE(1,0,1,1); STAGE(1,1,1,1);
  asm volatile("s_waitcnt vmcnt(8)" ::: "memory");      // t0 resident; t1 in flight
  BAR; SB0;

  bf16x8 aF[8], aS[8], bF[4], bS[4];
  // pre-read tile0 kh0 frags (aF,bF)
  #pragma unroll
  for (int m = 0; m < 8; ++m) aF[m] = LDV(ASEG(0,0) + laneA + m*512);
  #pragma unroll
  for (int n = 0; n < 4; ++n) bF[n] = LDV(BSEG(0,0) + laneB + n*512);

  for (int t = 0; t < NT; ++t){
    const int b = t & 1, bo = b ^ 1;

    // ---- R1(t): read kh1 frags (aS,bS) from buf b; stage A0,B0(t+2)->b;
    //             MFMA kh0 (aF x bF)
    BAR; SB0;
    #pragma unroll
    for (int m = 0; m < 8; ++m) aS[m] = LDV(ASEG(b,1) + laneA + m*512);
    #pragma unroll
    for (int n = 0; n < 4; ++n) bS[n] = LDV(BSEG(b,1) + laneB + n*512);
    if (t+2 < NT){ STAGE(b,0,0,t+2); STAGE(b,1,0,t+2); }
    PRIO1;
    #pragma unroll
    for (int m = 0; m < 8; ++m)
      #pragma unroll
      for (int n = 0; n < 4; ++n)
        acc[m][n] = MFMA(aF[m], bF[n], acc[m][n]);
    PRIO0;
    if (t < NT-2)       asm volatile("s_waitcnt vmcnt(8)" ::: "memory");
    else if (t == NT-2) asm volatile("s_waitcnt vmcnt(4)" ::: "memory");

    // ---- R2(t): read tile t+1 kh0 frags (aF,bF) from buf bo;
    //             stage A1,B1(t+2)->b; MFMA kh1 (aS x bS)
    BAR; SB0;
    if (t+1 < NT){
      #pragma unroll
      for (int m = 0; m < 8; ++m) aF[m] = LDV(ASEG(bo,0) + laneA + m*512);
      #pragma unroll
      for (int n = 0; n < 4; ++n) bF[n] = LDV(BSEG(bo,0) + laneB + n*512);
    }
    if (t+2 < NT){ STAGE(b,0,1,t+2); STAGE(b,1,1,t+2); }
    PRIO1;
    #pragma unroll
    for (int m = 0; m < 8; ++m)
      #pragma unroll
      for (int n = 0; n < 4; ++n)
        acc[m][n] = MFMA(aS[m], bS[n], acc[m][n]);
    PRIO0;
    if (t < NT-2)       asm volatile("s_waitcnt vmcnt(8)" ::: "memory");
    else if (t == NT-2) asm volatile("s_waitcnt vmcnt(0)" ::: "memory");
  }

  // ---- epilogue: C write (f32) ----
  const int orow = bm0 + wm*128 + (l>>4)*4;
  const int ocol = bn0 + wn*64  + (l&15);
  #pragma unroll
  for (int m = 0; m < 8; ++m)
    #pragma unroll
    for (int n = 0; n < 4; ++n)
      #pragma unroll
      for (int r = 0; r < 4; ++r)
        out[(size_t)(orow + m*16 + r)*DOUT + ocol + n*16] = acc[m][n][r];
  #undef LDV
  #undef ASEG
  #undef BSEG
}

// ---------------- fallback (ws too small): slow but correct fp32 ----------
__global__ void fb_t(const float* __restrict__ x, const float* __restrict__ mk,
                     const float* __restrict__ A, float* __restrict__ tf){
  const int m = blockIdx.x, t = threadIdx.x;
  float acc[RNK];
  #pragma unroll
  for (int r = 0; r < RNK; ++r) acc[r] = 0.f;
  for (int k = t; k < DIN; k += 256){
    float xm = x[(size_t)m*DIN + k] * mk[(size_t)m*DIN + k];
    #pragma unroll
    for (int r = 0; r < RNK; ++r) acc[r] += xm * A[(size_t)k*RNK + r];
  }
  #pragma unroll
  for (int r = 0; r < RNK; ++r){
    float v = acc[r];
    for (int o = 32; o; o >>= 1) v += __shfl_down(v, o);
    if ((t & 63) == 0) atomicAdd(&tf[(size_t)m*RNK + r], v);
  }
}

__global__ void fb_out(const float* __restrict__ x, const float* __restrict__ W,
                       const float* __restrict__ B, const float* __restrict__ tf,
                       float* __restrict__ out){
  size_t idx = (size_t)blockIdx.x*256 + threadIdx.x;
  int m = (int)(idx >> 12), n = (int)(idx & 4095);
  float acc = 0.f;
  for (int k = 0; k < DIN; ++k)
    acc += x[(size_t)m*DIN + k] * W[(size_t)n*DIN + k];
  #pragma unroll
  for (int r = 0; r < RNK; ++r)
    acc += tf[(size_t)m*RNK + r] * B[(size_t)r*DOUT + n];
  out[idx] = acc;
}

extern "C" void kernel_launch(void* const* d_in, const int* in_sizes, int n_in,
                              void* d_out, int out_size, void* d_ws, size_t ws_size,
                              hipStream_t stream) {
  const float* x  = (const float*)d_in[0];
  const float* W  = (const float*)d_in[1];
  const float* A  = (const float*)d_in[2];
  const float* B  = (const float*)d_in[3];
  const float* mk = (const float*)d_in[4];
  float* out = (float*)d_out;

  const size_t OFF_XB = 0;
  const size_t OFF_WB = OFF_XB + (size_t)MTOT*DIN*2;
  const size_t OFF_TB = OFF_WB + (size_t)DOUT*DIN*2;
  const size_t OFF_AT = OFF_TB + (size_t)MTOT*RNK*2;
  const size_t OFF_BT = OFF_AT + (size_t)RNK*DIN*2;
  const size_t NEED   = OFF_BT + (size_t)DIN*RNK*2;

  if (ws_size >= NEED){
    char* ws = (char*)d_ws;
    __hip_bfloat16* xb = (__hip_bfloat16*)(ws + OFF_XB);
    __hip_bfloat16* Wb = (__hip_bfloat16*)(ws + OFF_WB);
    __hip_bfloat16* tb = (__hip_bfloat16*)(ws + OFF_TB);
    __hip_bfloat16* At = (__hip_bfloat16*)(ws + OFF_AT);
    __hip_bfloat16* Bt = (__hip_bfloat16*)(ws + OFF_BT);

    k_conv_w <<<(DOUT*(size_t)DIN)/(256*8), 256, 0, stream>>>(W, Wb);
    k_conv_ab<<<(2*DIN*RNK)/256,            256, 0, stream>>>(A, B, At, Bt);
    k_xt     <<<MTOT/16,                    256, 0, stream>>>(x, mk, At, xb, tb);
    k_main7  <<<(MTOT/256)*(DOUT/256),      512, 0, stream>>>(xb, Wb, tb, Bt, out);
  } else {
    float* tf = (float*)d_ws;
    hipMemsetAsync(tf, 0, (size_t)MTOT*RNK*4, stream);
    fb_t  <<<MTOT, 256, 0, stream>>>(x, mk, A, tf);
    fb_out<<<((size_t)MTOT*DOUT)/256, 256, 0, stream>>>(x, W, B, tf, out);
  }
}